// Round 1
// baseline (237.910 us; speedup 1.0000x reference)
//
#include <hip/hip_runtime.h>
#include <cstdint>

#define LDS_XP 68      // x_bt pitch in shorts (34 dwords: stride%32==2 -> 2-way max, free; 8B aligned rows)
#define LDS_HP 82      // H pitch in shorts (41 dwords, odd -> conflict-free row access)
#define LT 64          // l-tile per block
#define HALO 8
#define XI (LT + 2*HALO)   // 80 staged positions
#define LX 16384
#define CC 64
#define NB 16

typedef __attribute__((ext_vector_type(8))) short s8;
typedef __attribute__((ext_vector_type(4))) short s4;
typedef __attribute__((ext_vector_type(4))) float f4;

static __device__ __forceinline__ short f2bf(float f) {
    union { float f; unsigned u; } v; v.f = f;
    unsigned r = v.u + 0x7FFFu + ((v.u >> 16) & 1u);   // RNE
    return (short)(r >> 16);
}
static __device__ __forceinline__ float bf2f(short s) {
    union { unsigned u; float f; } v;
    v.u = ((unsigned)(unsigned short)s) << 16;
    return v.f;
}

// ---------------- kernel 0: prep weight (bf16, [k][o][c] layout) + effective pw biases ----------------
__global__ void prep_kernel(const float* __restrict__ weight,
                            const float* __restrict__ b_off_pw, const float* __restrict__ w_off_pw,
                            const float* __restrict__ b_off_dw,
                            const float* __restrict__ b_msk_pw, const float* __restrict__ w_msk_pw,
                            const float* __restrict__ b_msk_dw,
                            short* __restrict__ A, float* __restrict__ beff) {
    int bid = blockIdx.x;
    if (bid < 48) {
        int idx = bid * 256 + threadIdx.x;        // 0..12287
        int k = idx >> 12;                        // /4096
        int rem = idx & 4095;
        int o = rem >> 6, c = rem & 63;
        A[idx] = f2bf(weight[o * 192 + c * 3 + k]);   // weight[o][c][k]
    } else {
        int t = threadIdx.x;
        if (t < 6) {
            int br = t / 3, m = t % 3;
            const float* pw = br ? w_msk_pw : w_off_pw;
            const float* bd = br ? b_msk_dw : b_off_dw;
            const float* bp = br ? b_msk_pw : b_off_pw;
            float s = bp[m];
            for (int c = 0; c < 64; ++c) s += pw[m * 64 + c] * bd[c];
            beff[t] = s;    // [0..2]=offset, [3..5]=mask
        }
    }
}

// ---------------- main fused kernel ----------------
__launch_bounds__(256, 2)
__global__ void deform_main(const float* __restrict__ x,
                            const float* __restrict__ w_off_dw, const float* __restrict__ w_off_pw,
                            const float* __restrict__ w_msk_dw, const float* __restrict__ w_msk_pw,
                            const float* __restrict__ bias,
                            const short* __restrict__ A, const float* __restrict__ beff,
                            float* __restrict__ out) {
    __shared__ short x_bt[XI * LDS_XP];            // bf16 x tile, [i][c]
    __shared__ short H[3 * 64 * LDS_HP];           // bf16 H_k[o][i]
    __shared__ float dwo[64 * 7], dwm[64 * 7];
    __shared__ float pwo[192], pwm[192];
    __shared__ float partial[2][4][3][64];         // [branch][cc][m][l]
    __shared__ float kl_w0[3][64], kl_w1[3][64];
    __shared__ int   kl_i0[3][64], kl_i1[3][64];
    __shared__ float bias_l[64];
    __shared__ float beff_l[6];

    const int t = threadIdx.x;
    const int tile = blockIdx.x;
    const int b = blockIdx.y;
    const int l0 = tile * LT;

    // ---- phase 0: stage x tile (coalesced along l), weights, biases ----
    const float* xb = x + (size_t)b * (CC * LX);
    for (int idx = t; idx < CC * XI; idx += 256) {
        int c = idx / XI, i = idx - c * XI;
        int g = l0 - HALO + i;
        float v = ((unsigned)g < (unsigned)LX) ? xb[c * LX + g] : 0.0f;
        x_bt[i * LDS_XP + c] = f2bf(v);
    }
    for (int idx = t; idx < 448; idx += 256) { dwo[idx] = w_off_dw[idx]; dwm[idx] = w_msk_dw[idx]; }
    if (t < 192) { pwo[t] = w_off_pw[t]; pwm[t] = w_msk_pw[t]; }
    if (t < 64) bias_l[t] = bias[t];
    if (t < 6)  beff_l[t] = beff[t];

    const int lane = t & 63;
    const int wv = t >> 6;           // wave id -> m-tile
    const int r = lane & 15, q = lane >> 4;
    const int m0 = wv * 16;

    // A fragments from global (L2-hot): A[k][m0+r][ks*32+q*8 .. +7]
    s8 afr[6];
    {
        const s8* Ap = (const s8*)A;
        #pragma unroll
        for (int k = 0; k < 3; ++k)
            #pragma unroll
            for (int ks = 0; ks < 2; ++ks)
                afr[k * 2 + ks] = Ap[((k * 64 + m0 + r) * 64 + ks * 32 + q * 8) >> 3];
    }

    __syncthreads();

    // ---- phase 2a: depthwise(k=7) + pointwise partials over c-chunk ----
    {
        const int l = t & 63, cc = t >> 6;
        float po0 = 0.f, po1 = 0.f, po2 = 0.f, pm0 = 0.f, pm1 = 0.f, pm2 = 0.f;
        #pragma unroll
        for (int ci = 0; ci < 16; ++ci) {
            int c = cc * 16 + ci;
            float so = 0.f, sm = 0.f;
            #pragma unroll
            for (int j = 0; j < 7; ++j) {
                float xv = bf2f(x_bt[(l + 5 + j) * LDS_XP + c]);   // global pos (l0+l)-3+j
                so += xv * dwo[c * 7 + j];
                sm += xv * dwm[c * 7 + j];
            }
            po0 += so * pwo[c];        pm0 += sm * pwm[c];
            po1 += so * pwo[64 + c];   pm1 += sm * pwm[64 + c];
            po2 += so * pwo[128 + c];  pm2 += sm * pwm[128 + c];
        }
        partial[0][cc][0][l] = po0; partial[0][cc][1][l] = po1; partial[0][cc][2][l] = po2;
        partial[1][cc][0][l] = pm0; partial[1][cc][1][l] = pm1; partial[1][cc][2][l] = pm2;
    }

    // ---- phase 3: H_k = W_k @ x  (MFMA, M=64 N=80 K=64) ----
    {
        s8 bfr[10];
        #pragma unroll
        for (int n = 0; n < 5; ++n)
            #pragma unroll
            for (int ks = 0; ks < 2; ++ks) {
                int base = (n * 16 + r) * LDS_XP + ks * 32 + q * 8;
                s4 lo = *(const s4*)&x_bt[base];
                s4 hi = *(const s4*)&x_bt[base + 4];
                s8 f;
                f[0] = lo[0]; f[1] = lo[1]; f[2] = lo[2]; f[3] = lo[3];
                f[4] = hi[0]; f[5] = hi[1]; f[6] = hi[2]; f[7] = hi[3];
                bfr[n * 2 + ks] = f;
            }
        #pragma unroll
        for (int k = 0; k < 3; ++k) {
            #pragma unroll
            for (int n = 0; n < 5; ++n) {
                f4 acc = {0.f, 0.f, 0.f, 0.f};
                acc = __builtin_amdgcn_mfma_f32_16x16x32_bf16(afr[k * 2 + 0], bfr[n * 2 + 0], acc, 0, 0, 0);
                acc = __builtin_amdgcn_mfma_f32_16x16x32_bf16(afr[k * 2 + 1], bfr[n * 2 + 1], acc, 0, 0, 0);
                #pragma unroll
                for (int e = 0; e < 4; ++e) {
                    int o = m0 + q * 4 + e;                 // D row = (lane>>4)*4 + reg
                    H[(k * 64 + o) * LDS_HP + n * 16 + r] = f2bf(acc[e]);   // D col = lane&15
                }
            }
        }
    }

    __syncthreads();

    // ---- phase 2b: reduce partials, sigmoid, interpolation coefficients ----
    if (t < 192) {
        int k = t >> 6, l = t & 63;
        float off = beff_l[k]
                  + partial[0][0][k][l] + partial[0][1][k][l] + partial[0][2][k][l] + partial[0][3][k][l];
        float z   = beff_l[3 + k]
                  + partial[1][0][k][l] + partial[1][1][k][l] + partial[1][2][k][l] + partial[1][3][k][l];
        float msk = 1.0f / (1.0f + __expf(-z));
        float p = (float)(l0 + l - 1 + k) + off;   // base + kpos + offset (same op order as ref)
        float fl = floorf(p);
        int i0 = (int)fl, i1 = i0 + 1;
        float fr = p - fl;
        int li0 = i0 - l0 + HALO, li1 = li0 + 1;
        float w0 = (((unsigned)i0 < (unsigned)LX) && ((unsigned)li0 < (unsigned)XI)) ? (1.0f - fr) * msk : 0.0f;
        float w1 = (((unsigned)i1 < (unsigned)LX) && ((unsigned)li1 < (unsigned)XI)) ? fr * msk : 0.0f;
        li0 = min(max(li0, 0), XI - 1);
        li1 = min(max(li1, 0), XI - 1);
        kl_w0[k][l] = w0; kl_w1[k][l] = w1; kl_i0[k][l] = li0; kl_i1[k][l] = li1;
    }

    __syncthreads();

    // ---- phase 4: epilogue — gather H, combine taps, add bias, store ----
    {
        int l = t & 63, og = t >> 6;
        float w0a[3], w1a[3]; int i0a[3], i1a[3];
        #pragma unroll
        for (int k = 0; k < 3; ++k) {
            w0a[k] = kl_w0[k][l]; w1a[k] = kl_w1[k][l];
            i0a[k] = kl_i0[k][l]; i1a[k] = kl_i1[k][l];
        }
        float* ob = out + ((size_t)b * 64 + og * 16) * LX + l0 + l;
        #pragma unroll
        for (int oi = 0; oi < 16; ++oi) {
            int o = og * 16 + oi;
            float acc = bias_l[o];
            #pragma unroll
            for (int k = 0; k < 3; ++k) {
                const short* Hr = &H[(k * 64 + o) * LDS_HP];
                acc += w0a[k] * bf2f(Hr[i0a[k]]) + w1a[k] * bf2f(Hr[i1a[k]]);
            }
            ob[(size_t)oi * LX] = acc;   // lanes: consecutive l -> coalesced 256B per store
        }
    }
}

extern "C" void kernel_launch(void* const* d_in, const int* in_sizes, int n_in,
                              void* d_out, int out_size, void* d_ws, size_t ws_size,
                              hipStream_t stream) {
    const float* x        = (const float*)d_in[0];
    const float* w_off_dw = (const float*)d_in[1];
    const float* b_off_dw = (const float*)d_in[2];
    const float* w_off_pw = (const float*)d_in[3];
    const float* b_off_pw = (const float*)d_in[4];
    const float* w_msk_dw = (const float*)d_in[5];
    const float* b_msk_dw = (const float*)d_in[6];
    const float* w_msk_pw = (const float*)d_in[7];
    const float* b_msk_pw = (const float*)d_in[8];
    const float* weight   = (const float*)d_in[9];
    const float* bias     = (const float*)d_in[10];
    float* out = (float*)d_out;

    short* A    = (short*)d_ws;                       // 12288 bf16 = 24576 B
    float* beff = (float*)((char*)d_ws + 24576);      // 6 floats

    hipLaunchKernelGGL(prep_kernel, dim3(49), dim3(256), 0, stream,
                       weight, b_off_pw, w_off_pw, b_off_dw, b_msk_pw, w_msk_pw, b_msk_dw, A, beff);
    hipLaunchKernelGGL(deform_main, dim3(LX / LT, NB), dim3(256), 0, stream,
                       x, w_off_dw, w_off_pw, w_msk_dw, w_msk_pw, bias, A, beff, out);
}

// Round 2
// 189.365 us; speedup vs baseline: 1.2564x; 1.2564x over previous
//
#include <hip/hip_runtime.h>
#include <cstdint>

#define LX 16384
#define CC 64
#define NB 16
#define LT 64
#define HALO 8
#define XI (LT + 2*HALO)     // 80 staged positions
#define XP 68                // x_bt pitch in shorts (136 B/row: 8B-aligned rows)
#define HP 68                // H pitch in shorts ([k][i][o] layout)

typedef __attribute__((ext_vector_type(8))) short s8;
typedef __attribute__((ext_vector_type(4))) short s4;
typedef __attribute__((ext_vector_type(4))) float f4;

union frag8 { s8 v; s4 h[2]; };

static __device__ __forceinline__ short f2bf(float f) {
    union { float f; unsigned u; } v; v.f = f;
    unsigned r = v.u + 0x7FFFu + ((v.u >> 16) & 1u);   // RNE
    return (short)(r >> 16);
}
static __device__ __forceinline__ float bflo(unsigned d) {
    union { unsigned u; float f; } v; v.u = d << 16; return v.f;
}
static __device__ __forceinline__ float bfhi(unsigned d) {
    union { unsigned u; float f; } v; v.u = d & 0xFFFF0000u; return v.f;
}

// ---------------- kernel 0: prep weights into ws ----------------
// ws layout: A bf16[3][64][64] @0 (24576 B) | beff f32[6] @24576 | dwt f32[896] @24608
//            (dwt[br*448 + j*64 + c] = w_dw[c*7+j]) | pwx f32[512] @28192
//            (pwx[c*8+m] = w_off_pw[m*64+c], pwx[c*8+4+m] = w_msk_pw[m*64+c])
__global__ void prep_kernel(const float* __restrict__ weight,
                            const float* __restrict__ b_off_pw, const float* __restrict__ w_off_pw,
                            const float* __restrict__ b_off_dw,
                            const float* __restrict__ b_msk_pw, const float* __restrict__ w_msk_pw,
                            const float* __restrict__ b_msk_dw,
                            const float* __restrict__ w_off_dw, const float* __restrict__ w_msk_dw,
                            short* __restrict__ A, float* __restrict__ beff,
                            float* __restrict__ dwt, float* __restrict__ pwx) {
    int bid = blockIdx.x;
    int t = threadIdx.x;
    if (bid < 48) {
        int idx = bid * 256 + t;                  // 0..12287
        int k = idx >> 12;
        int rem = idx & 4095;
        int o = rem >> 6, c = rem & 63;
        A[idx] = f2bf(weight[o * 192 + c * 3 + k]);   // weight[o][c][k] -> A[k][o][c]
    } else {
        for (int idx = t; idx < 896; idx += 256) {
            int br = idx / 448, r2 = idx - br * 448;
            int j = r2 >> 6, c = r2 & 63;
            const float* src = br ? w_msk_dw : w_off_dw;
            dwt[idx] = src[c * 7 + j];
        }
        for (int idx = t; idx < 512; idx += 256) {
            int c = idx >> 3, m = idx & 7;
            float v = 0.0f;
            if (m < 3) v = w_off_pw[m * 64 + c];
            else if (m >= 4 && m < 7) v = w_msk_pw[(m - 4) * 64 + c];
            pwx[idx] = v;
        }
        if (t < 6) {
            int br = t / 3, m = t % 3;
            const float* pw = br ? w_msk_pw : w_off_pw;
            const float* bd = br ? b_msk_dw : b_off_dw;
            const float* bp = br ? b_msk_pw : b_off_pw;
            float s = bp[m];
            for (int c = 0; c < 64; ++c) s += pw[m * 64 + c] * bd[c];
            beff[t] = s;    // [0..2]=offset, [3..5]=mask
        }
    }
}

// ---------------- main fused kernel ----------------
__launch_bounds__(256, 3)
__global__ void deform_main(const float* __restrict__ x,
                            const float* __restrict__ bias,
                            const short* __restrict__ A,
                            const float* __restrict__ beff,
                            const float* __restrict__ dwt_g,
                            const float* __restrict__ pwx_g,
                            float* __restrict__ out) {
    __shared__ short x_bt[XI * XP];          // 10880 B  [i][c] bf16
    __shared__ short H[3 * XI * HP];         // 32640 B  [k][i][o] bf16
    __shared__ float dwt[896];               // 3584 B   [br][j][c]
    __shared__ float pwx[512];               // 2048 B   [c][{off0..2,0,msk0..2,0}]
    __shared__ float kl_w0[3][64], kl_w1[3][64];   // 1536 B
    __shared__ int   kl_i0[3][64], kl_i1[3][64];   // 1536 B
    __shared__ float bias_l[64];             // 256 B
    __shared__ float beff_l[8];              // 32 B
    // total 52512 B -> 3 blocks/CU

    const int t = threadIdx.x;
    const int l0 = blockIdx.x * LT;
    const int b = blockIdx.y;

    // ---- phase 0: stage x tile (float4 global loads), weights, biases ----
    const float* xb = x + (size_t)b * (CC * LX);
    #pragma unroll
    for (int s = 0; s < 5; ++s) {
        int idx4 = t + 256 * s;                 // [0,1280): 64 rows x 20 float4
        int c = (int)((unsigned)idx4 / 20u);
        int u = idx4 - c * 20;
        int g4 = l0 - HALO + u * 4;
        f4 v = {0.f, 0.f, 0.f, 0.f};
        if ((unsigned)g4 < (unsigned)LX) v = *(const f4*)(xb + c * LX + g4);
        #pragma unroll
        for (int d = 0; d < 4; ++d)
            x_bt[(u * 4 + d) * XP + c] = f2bf(v[d]);
    }
    for (int idx = t; idx < 896; idx += 256) dwt[idx] = dwt_g[idx];
    pwx[t] = pwx_g[t];
    pwx[t + 256] = pwx_g[t + 256];
    if (t < 64) bias_l[t] = bias[t];
    if (t < 6)  beff_l[t] = beff[t];
    __syncthreads();

    // ---- phase 2: offset/mask conv (vectorized LDS) + in-wave reduce + coefs ----
    {
        const int l = t >> 2, cc = t & 3;       // 64 l-positions x 4 c-chunks
        float so[16], sm[16];
        #pragma unroll
        for (int i = 0; i < 16; ++i) { so[i] = 0.f; sm[i] = 0.f; }
        #pragma unroll
        for (int j = 0; j < 7; ++j) {
            const short* xr = &x_bt[(l + 5 + j) * XP + cc * 16];  // global pos (l0+l)-3+j
            const float* wo = &dwt[j * 64 + cc * 16];
            const float* wm = &dwt[448 + j * 64 + cc * 16];
            #pragma unroll
            for (int u = 0; u < 4; ++u) {
                union { s4 v; unsigned d[2]; } X;
                X.v = *(const s4*)(xr + u * 4);
                f4 wov = *(const f4*)(wo + u * 4);
                f4 wmv = *(const f4*)(wm + u * 4);
                float x0 = bflo(X.d[0]), x1 = bfhi(X.d[0]);
                float x2 = bflo(X.d[1]), x3 = bfhi(X.d[1]);
                so[u*4+0] += x0 * wov[0];  sm[u*4+0] += x0 * wmv[0];
                so[u*4+1] += x1 * wov[1];  sm[u*4+1] += x1 * wmv[1];
                so[u*4+2] += x2 * wov[2];  sm[u*4+2] += x2 * wmv[2];
                so[u*4+3] += x3 * wov[3];  sm[u*4+3] += x3 * wmv[3];
            }
        }
        float po0=0.f, po1=0.f, po2=0.f, pm0=0.f, pm1=0.f, pm2=0.f;
        #pragma unroll
        for (int ci = 0; ci < 16; ++ci) {
            const float* pr = &pwx[(cc * 16 + ci) * 8];
            f4 p0 = *(const f4*)pr;
            f4 p1 = *(const f4*)(pr + 4);
            po0 += so[ci] * p0[0];  po1 += so[ci] * p0[1];  po2 += so[ci] * p0[2];
            pm0 += sm[ci] * p1[0];  pm1 += sm[ci] * p1[1];  pm2 += sm[ci] * p1[2];
        }
        // butterfly over the 4 cc-lanes (same wave)
        #pragma unroll
        for (int d = 1; d <= 2; d <<= 1) {
            po0 += __shfl_xor(po0, d); po1 += __shfl_xor(po1, d); po2 += __shfl_xor(po2, d);
            pm0 += __shfl_xor(pm0, d); pm1 += __shfl_xor(pm1, d); pm2 += __shfl_xor(pm2, d);
        }
        if (cc < 3) {
            int k = cc;
            float off = (cc == 0 ? po0 : cc == 1 ? po1 : po2) + beff_l[k];
            float z   = (cc == 0 ? pm0 : cc == 1 ? pm1 : pm2) + beff_l[3 + k];
            float msk = 1.0f / (1.0f + __expf(-z));
            float p = (float)(l0 + l - 1 + k) + off;   // base + kpos + offset (ref op order)
            float fl = floorf(p);
            int i0 = (int)fl, i1 = i0 + 1;
            float fr = p - fl;
            int li0 = i0 - l0 + HALO, li1 = li0 + 1;
            float w0 = (((unsigned)i0 < (unsigned)LX) && ((unsigned)li0 < (unsigned)XI)) ? (1.0f - fr) * msk : 0.0f;
            float w1 = (((unsigned)i1 < (unsigned)LX) && ((unsigned)li1 < (unsigned)XI)) ? fr * msk : 0.0f;
            li0 = min(max(li0, 0), XI - 1);
            li1 = min(max(li1, 0), XI - 1);
            kl_w0[k][l] = w0; kl_w1[k][l] = w1; kl_i0[k][l] = li0; kl_i1[k][l] = li1;
        }
    }

    // ---- phase 3: H_k = W_k @ x  (MFMA, M=64 N=80 K=64), H -> [k][i][o] ----
    {
        const int lane = t & 63, wv = t >> 6;
        const int r = lane & 15, q = lane >> 4;
        const int m0 = wv * 16;
        s8 afr[6];
        {
            const s8* Ap = (const s8*)A;
            #pragma unroll
            for (int k = 0; k < 3; ++k)
                #pragma unroll
                for (int ks = 0; ks < 2; ++ks)
                    afr[k * 2 + ks] = Ap[((k * 64 + m0 + r) * 64 + ks * 32 + q * 8) >> 3];
        }
        frag8 bfr[10];
        #pragma unroll
        for (int n = 0; n < 5; ++n)
            #pragma unroll
            for (int ks = 0; ks < 2; ++ks) {
                const short* base = &x_bt[(n * 16 + r) * XP + ks * 32 + q * 8];
                bfr[n * 2 + ks].h[0] = *(const s4*)base;
                bfr[n * 2 + ks].h[1] = *(const s4*)(base + 4);
            }
        #pragma unroll
        for (int k = 0; k < 3; ++k) {
            #pragma unroll
            for (int n = 0; n < 5; ++n) {
                f4 acc = {0.f, 0.f, 0.f, 0.f};
                acc = __builtin_amdgcn_mfma_f32_16x16x32_bf16(afr[k * 2 + 0], bfr[n * 2 + 0].v, acc, 0, 0, 0);
                acc = __builtin_amdgcn_mfma_f32_16x16x32_bf16(afr[k * 2 + 1], bfr[n * 2 + 1].v, acc, 0, 0, 0);
                s4 hv;
                #pragma unroll
                for (int e = 0; e < 4; ++e) hv[e] = f2bf(acc[e]);   // D row o = m0+4q+e, col i = n*16+r
                *(s4*)&H[(k * XI + n * 16 + r) * HP + m0 + 4 * q] = hv;   // one ds_write_b64
            }
        }
    }
    __syncthreads();

    // ---- phase 4: epilogue — vectorized H gather, combine taps, bias, store ----
    {
        const int l = t & 63, og = t >> 6;
        float acc[16];
        #pragma unroll
        for (int oi = 0; oi < 16; ++oi) acc[oi] = bias_l[og * 16 + oi];
        #pragma unroll
        for (int k = 0; k < 3; ++k) {
            float w0 = kl_w0[k][l], w1 = kl_w1[k][l];
            int li0 = kl_i0[k][l], li1 = kl_i1[k][l];
            const short* r0 = &H[(k * XI + li0) * HP + og * 16];
            const short* r1 = &H[(k * XI + li1) * HP + og * 16];
            #pragma unroll
            for (int u = 0; u < 4; ++u) {
                union { s4 v; unsigned d[2]; } A0, A1;
                A0.v = *(const s4*)(r0 + u * 4);
                A1.v = *(const s4*)(r1 + u * 4);
                acc[u*4+0] += w0 * bflo(A0.d[0]) + w1 * bflo(A1.d[0]);
                acc[u*4+1] += w0 * bfhi(A0.d[0]) + w1 * bfhi(A1.d[0]);
                acc[u*4+2] += w0 * bflo(A0.d[1]) + w1 * bflo(A1.d[1]);
                acc[u*4+3] += w0 * bfhi(A0.d[1]) + w1 * bfhi(A1.d[1]);
            }
        }
        float* ob = out + ((size_t)b * 64 + og * 16) * LX + l0 + l;
        #pragma unroll
        for (int oi = 0; oi < 16; ++oi) ob[(size_t)oi * LX] = acc[oi];   // coalesced 256B/instr
    }
}

extern "C" void kernel_launch(void* const* d_in, const int* in_sizes, int n_in,
                              void* d_out, int out_size, void* d_ws, size_t ws_size,
                              hipStream_t stream) {
    const float* x        = (const float*)d_in[0];
    const float* w_off_dw = (const float*)d_in[1];
    const float* b_off_dw = (const float*)d_in[2];
    const float* w_off_pw = (const float*)d_in[3];
    const float* b_off_pw = (const float*)d_in[4];
    const float* w_msk_dw = (const float*)d_in[5];
    const float* b_msk_dw = (const float*)d_in[6];
    const float* w_msk_pw = (const float*)d_in[7];
    const float* b_msk_pw = (const float*)d_in[8];
    const float* weight   = (const float*)d_in[9];
    const float* bias     = (const float*)d_in[10];
    float* out = (float*)d_out;

    short* A    = (short*)d_ws;                        // 24576 B
    float* beff = (float*)((char*)d_ws + 24576);       // 24 B
    float* dwt  = (float*)((char*)d_ws + 24608);       // 3584 B
    float* pwx  = (float*)((char*)d_ws + 28192);       // 2048 B

    hipLaunchKernelGGL(prep_kernel, dim3(49), dim3(256), 0, stream,
                       weight, b_off_pw, w_off_pw, b_off_dw, b_msk_pw, w_msk_pw, b_msk_dw,
                       w_off_dw, w_msk_dw, A, beff, dwt, pwx);
    hipLaunchKernelGGL(deform_main, dim3(LX / LT, NB), dim3(256), 0, stream,
                       x, bias, A, beff, dwt, pwx, out);
}

// Round 4
// 158.188 us; speedup vs baseline: 1.5040x; 1.1971x over previous
//
#include <hip/hip_runtime.h>
#include <cstdint>

#define LX 16384
#define NB 16
#define LT 64
#define HALO 8
#define XI (LT + 2*HALO)     // 80 staged positions
#define XPD 36               // x row pitch in dwords (144 B, 16B-aligned, 32 data + 4 pad)
#define HPD 36               // H row pitch in dwords

typedef __attribute__((ext_vector_type(2))) _Float16 h2;
typedef __attribute__((ext_vector_type(8))) _Float16 h8;
typedef __attribute__((ext_vector_type(4))) unsigned u4;
typedef __attribute__((ext_vector_type(4))) float f4;

static __device__ __forceinline__ h2 u2h(unsigned u) {
    union { unsigned u; h2 h; } v; v.u = u; return v.h;
}
static __device__ __forceinline__ unsigned h2u(h2 h) {
    union { h2 h; unsigned u; } v; v.h = h; return v.u;
}
static __device__ __forceinline__ unsigned pkrtz(float a, float b) {
    auto r = __builtin_amdgcn_cvt_pkrtz(a, b);        // __fp16 ext_vector(2)
    union { decltype(r) h; unsigned u; } v; v.h = r;  // bitcast, no type conversion
    return v.u;
}

// ---------------- kernel 0: prep weights into ws (all f16) ----------------
// ws: A f16[3][64][64] @0 (24576 B) | beff f32[6] @24576 | dwt2 u32[448] @24608
//     (dwt2[(br*7+j)*32+cp] = half2(w_dw[2cp][j], w_dw[2cp+1][j]))
//     | pwt2 u32[192] @26400 (pwt2[(br*3+m)*32+cp] = half2(pw[m][2cp], pw[m][2cp+1]))
__global__ void prep_kernel(const float* __restrict__ weight,
                            const float* __restrict__ b_off_pw, const float* __restrict__ w_off_pw,
                            const float* __restrict__ b_off_dw,
                            const float* __restrict__ b_msk_pw, const float* __restrict__ w_msk_pw,
                            const float* __restrict__ b_msk_dw,
                            const float* __restrict__ w_off_dw, const float* __restrict__ w_msk_dw,
                            short* __restrict__ A, float* __restrict__ beff,
                            unsigned* __restrict__ dwt2, unsigned* __restrict__ pwt2) {
    int bid = blockIdx.x;
    int t = threadIdx.x;
    if (bid < 48) {
        int idx = bid * 256 + t;                  // 0..12287 : A[k][o][c]
        int k = idx >> 12;
        int o = (idx >> 6) & 63, c = idx & 63;
        union { _Float16 h; short s; } v;
        v.h = (_Float16)weight[o * 192 + c * 3 + k];   // weight[o][c][k]
        A[idx] = v.s;
    } else {
        for (int idx = t; idx < 448; idx += 256) {
            int br = idx / 224, r2 = idx - br * 224;
            int j = r2 >> 5, cp = r2 & 31;
            const float* src = br ? w_msk_dw : w_off_dw;
            h2 h; h[0] = (_Float16)src[(2 * cp) * 7 + j]; h[1] = (_Float16)src[(2 * cp + 1) * 7 + j];
            dwt2[idx] = h2u(h);
        }
        if (t < 192) {
            int br = t / 96, r2 = t - br * 96;
            int m = r2 >> 5, cp = r2 & 31;
            const float* src = br ? w_msk_pw : w_off_pw;
            h2 h; h[0] = (_Float16)src[m * 64 + 2 * cp]; h[1] = (_Float16)src[m * 64 + 2 * cp + 1];
            pwt2[t] = h2u(h);
        }
        if (t < 6) {
            int br = t / 3, m = t % 3;
            const float* pw = br ? w_msk_pw : w_off_pw;
            const float* bd = br ? b_msk_dw : b_off_dw;
            const float* bp = br ? b_msk_pw : b_off_pw;
            float s = bp[m];
            for (int c = 0; c < 64; ++c) s += pw[m * 64 + c] * bd[c];
            beff[t] = s;
        }
    }
}

// ---------------- main fused kernel ----------------
__launch_bounds__(256, 3)
__global__ void deform_main(const float* __restrict__ x,
                            const float* __restrict__ bias,
                            const short* __restrict__ A,
                            const float* __restrict__ beff,
                            const unsigned* __restrict__ dwt2_g,
                            const unsigned* __restrict__ pwt2_g,
                            float* __restrict__ out) {
    // x tile f16 [i][c], c-pairs as dwords; chunk(8 dw)-rotated by row: phys = (chunk + i) & 3
    __shared__ __align__(16) unsigned xdw[XI * XPD];        // 11520 B
    // H f16 [k][i][o]; o-chunk rotated by row: phys = (chunk + i) & 3
    __shared__ __align__(16) unsigned Hdw[3 * XI * HPD];    // 34560 B
    __shared__ __align__(16) unsigned dwt2[448];            // 1792 B [br][j][cpair]
    __shared__ __align__(16) unsigned pwt2[192];            // 768 B  [br][m][cpair]
    __shared__ unsigned kl_wp[3][64];                       // 768 B  half2(w0,w1)
    __shared__ int      kl_li[3][64];                       // 768 B
    __shared__ float bias_l[64];                            // 256 B
    __shared__ float beff_l[8];                             // 32 B
    // total 50464 B -> 3 blocks/CU

    const int t = threadIdx.x;
    const int l0 = blockIdx.x * LT;
    const int b = blockIdx.y;

    // ---- phase 0: stage x tile ----
    // p in [0,640): cp = p&31 (c-pair), up = p>>5 (i-quad 0..19)
    // global: 2 float4 rows 2cp,2cp+1; LDS: 4x ds_write_b32, 2-way (free) banks
    const float* xb = x + (size_t)b * (64 * LX);
    #pragma unroll
    for (int s = 0; s < 3; ++s) {
        int p = t + 256 * s;
        if (p < 640) {
            int cp = p & 31, up = p >> 5;
            int g4 = l0 - HALO + up * 4;
            f4 v0 = {0.f, 0.f, 0.f, 0.f}, v1 = {0.f, 0.f, 0.f, 0.f};
            if ((unsigned)g4 < (unsigned)LX) {
                v0 = *(const f4*)(xb + (size_t)(2 * cp) * LX + g4);
                v1 = *(const f4*)(xb + (size_t)(2 * cp + 1) * LX + g4);
            }
            #pragma unroll
            for (int d = 0; d < 4; ++d) {
                int i = up * 4 + d;
                int pc = ((cp >> 3) + i) & 3;
                xdw[i * XPD + pc * 8 + (cp & 7)] = pkrtz(v0[d], v1[d]);
            }
        }
    }
    for (int idx = t; idx < 448; idx += 256) dwt2[idx] = dwt2_g[idx];
    if (t < 192) pwt2[t] = pwt2_g[t];
    if (t < 64) bias_l[t] = bias[t];
    if (t < 6)  beff_l[t] = beff[t];

    // A fragments (global, L2-hot), independent of LDS
    const int lane = t & 63;
    const int wv = t >> 6;
    const int r = lane & 15, q = lane >> 4;
    const int m0 = wv * 16;
    h8 afr[6];
    {
        const h8* Ap = (const h8*)A;
        #pragma unroll
        for (int k = 0; k < 3; ++k)
            #pragma unroll
            for (int ks = 0; ks < 2; ++ks)
                afr[k * 2 + ks] = Ap[(k * 64 + m0 + r) * 8 + ks * 4 + q];
    }
    __syncthreads();

    // ---- phase 2: offset/mask conv (pk_fma_f16 + fdot2) + butterfly + coefs ----
    {
        const int l = t >> 2, cc = t & 3;
        h2 so2[8], sm2[8];
        #pragma unroll
        for (int m = 0; m < 8; ++m) { so2[m] = (h2)(_Float16)0; sm2[m] = (h2)(_Float16)0; }
        #pragma unroll
        for (int j = 0; j < 7; ++j) {
            int i = l + 5 + j;                         // global pos (l0+l)-3+j
            const unsigned* xr = &xdw[i * XPD + (((cc + i) & 3) << 3)];
            u4 xa = *(const u4*)xr;
            u4 xb2 = *(const u4*)(xr + 4);
            const unsigned* wo = &dwt2[j * 32 + cc * 8];
            const unsigned* wm = &dwt2[224 + j * 32 + cc * 8];
            u4 woa = *(const u4*)wo, wob = *(const u4*)(wo + 4);
            u4 wma = *(const u4*)wm, wmb = *(const u4*)(wm + 4);
            #pragma unroll
            for (int m = 0; m < 4; ++m) {
                so2[m]     += u2h(xa[m])  * u2h(woa[m]);
                so2[m + 4] += u2h(xb2[m]) * u2h(wob[m]);
                sm2[m]     += u2h(xa[m])  * u2h(wma[m]);
                sm2[m + 4] += u2h(xb2[m]) * u2h(wmb[m]);
            }
        }
        float po[3] = {0.f, 0.f, 0.f}, pm[3] = {0.f, 0.f, 0.f};
        #pragma unroll
        for (int m3 = 0; m3 < 3; ++m3) {
            const unsigned* p0 = &pwt2[m3 * 32 + cc * 8];
            const unsigned* p1 = &pwt2[96 + m3 * 32 + cc * 8];
            u4 a0 = *(const u4*)p0, a1 = *(const u4*)(p0 + 4);
            u4 b0 = *(const u4*)p1, b1 = *(const u4*)(p1 + 4);
            #pragma unroll
            for (int m = 0; m < 4; ++m) {
                po[m3] = __builtin_amdgcn_fdot2(so2[m],     u2h(a0[m]), po[m3], false);
                po[m3] = __builtin_amdgcn_fdot2(so2[m + 4], u2h(a1[m]), po[m3], false);
                pm[m3] = __builtin_amdgcn_fdot2(sm2[m],     u2h(b0[m]), pm[m3], false);
                pm[m3] = __builtin_amdgcn_fdot2(sm2[m + 4], u2h(b1[m]), pm[m3], false);
            }
        }
        #pragma unroll
        for (int d = 1; d <= 2; d <<= 1) {
            #pragma unroll
            for (int m3 = 0; m3 < 3; ++m3) {
                po[m3] += __shfl_xor(po[m3], d);
                pm[m3] += __shfl_xor(pm[m3], d);
            }
        }
        if (cc < 3) {
            int k = cc;
            float off = (k == 0 ? po[0] : k == 1 ? po[1] : po[2]) + beff_l[k];
            float z   = (k == 0 ? pm[0] : k == 1 ? pm[1] : pm[2]) + beff_l[3 + k];
            float msk = 1.0f / (1.0f + __expf(-z));
            float p = (float)(l0 + l - 1 + k) + off;   // ref op order
            float fl = floorf(p);
            int i0 = (int)fl, i1 = i0 + 1;
            float fr = p - fl;
            int li0 = i0 - l0 + HALO, li1 = li0 + 1;
            float w0 = (((unsigned)i0 < (unsigned)LX) && ((unsigned)li0 < (unsigned)XI)) ? (1.0f - fr) * msk : 0.0f;
            float w1 = (((unsigned)i1 < (unsigned)LX) && ((unsigned)li1 < (unsigned)XI)) ? fr * msk : 0.0f;
            li0 = min(max(li0, 0), XI - 2);            // rows li0, li0+1 both staged
            kl_wp[k][l] = pkrtz(w0, w1);
            kl_li[k][l] = li0;
        }
    }

    // ---- phase 3: H_k = W_k @ x  (f16 MFMA, M=64 N=80 K=64) -> Hdw [k][i][o] ----
    {
        h8 bfr[10];
        #pragma unroll
        for (int n = 0; n < 5; ++n)
            #pragma unroll
            for (int ks = 0; ks < 2; ++ks) {
                int i = n * 16 + r;
                int pc = ((2 * ks + (q >> 1)) + i) & 3;
                bfr[n * 2 + ks] = *(const h8*)&xdw[i * XPD + pc * 8 + (q & 1) * 4];
            }
        #pragma unroll
        for (int k = 0; k < 3; ++k) {
            #pragma unroll
            for (int n = 0; n < 5; ++n) {
                f4 acc = {0.f, 0.f, 0.f, 0.f};
                acc = __builtin_amdgcn_mfma_f32_16x16x32_f16(afr[k * 2 + 0], bfr[n * 2 + 0], acc, 0, 0, 0);
                acc = __builtin_amdgcn_mfma_f32_16x16x32_f16(afr[k * 2 + 1], bfr[n * 2 + 1], acc, 0, 0, 0);
                int i = n * 16 + r;                     // D col = i, row o = m0 + 4q + e
                int pc = (wv + i) & 3;
                unsigned* dst = &Hdw[(k * XI + i) * HPD + pc * 8 + 2 * q];
                dst[0] = pkrtz(acc[0], acc[1]);
                dst[1] = pkrtz(acc[2], acc[3]);
            }
        }
    }
    __syncthreads();

    // ---- phase 4: epilogue — H gather via v_perm + fdot2, bias, store ----
    {
        const int l = t & 63, og = t >> 6;
        float acc[16];
        #pragma unroll
        for (int oi = 0; oi < 16; ++oi) acc[oi] = bias_l[og * 16 + oi];
        #pragma unroll
        for (int k = 0; k < 3; ++k) {
            h2 wph = u2h(kl_wp[k][l]);                  // (w0, w1)
            int li0 = kl_li[k][l];
            int b0 = (k * XI + li0) * HPD + (((og + li0) & 3) << 3);
            int b1 = (k * XI + li0 + 1) * HPD + (((og + li0 + 1) & 3) << 3);
            u4 r0a = *(const u4*)&Hdw[b0], r0b = *(const u4*)&Hdw[b0 + 4];
            u4 r1a = *(const u4*)&Hdw[b1], r1b = *(const u4*)&Hdw[b1 + 4];
            #pragma unroll
            for (int m = 0; m < 4; ++m) {
                unsigned dA0 = __builtin_amdgcn_perm(r1a[m], r0a[m], 0x05040100u);  // (h0,h1) even o
                unsigned dA1 = __builtin_amdgcn_perm(r1a[m], r0a[m], 0x07060302u);  // odd o
                acc[2 * m]     = __builtin_amdgcn_fdot2(u2h(dA0), wph, acc[2 * m], false);
                acc[2 * m + 1] = __builtin_amdgcn_fdot2(u2h(dA1), wph, acc[2 * m + 1], false);
                unsigned dB0 = __builtin_amdgcn_perm(r1b[m], r0b[m], 0x05040100u);
                unsigned dB1 = __builtin_amdgcn_perm(r1b[m], r0b[m], 0x07060302u);
                acc[8 + 2 * m]     = __builtin_amdgcn_fdot2(u2h(dB0), wph, acc[8 + 2 * m], false);
                acc[8 + 2 * m + 1] = __builtin_amdgcn_fdot2(u2h(dB1), wph, acc[8 + 2 * m + 1], false);
            }
        }
        float* ob = out + ((size_t)b * 64 + og * 16) * LX + l0 + l;
        #pragma unroll
        for (int oi = 0; oi < 16; ++oi) ob[(size_t)oi * LX] = acc[oi];
    }
}

extern "C" void kernel_launch(void* const* d_in, const int* in_sizes, int n_in,
                              void* d_out, int out_size, void* d_ws, size_t ws_size,
                              hipStream_t stream) {
    const float* x        = (const float*)d_in[0];
    const float* w_off_dw = (const float*)d_in[1];
    const float* b_off_dw = (const float*)d_in[2];
    const float* w_off_pw = (const float*)d_in[3];
    const float* b_off_pw = (const float*)d_in[4];
    const float* w_msk_dw = (const float*)d_in[5];
    const float* b_msk_dw = (const float*)d_in[6];
    const float* w_msk_pw = (const float*)d_in[7];
    const float* b_msk_pw = (const float*)d_in[8];
    const float* weight   = (const float*)d_in[9];
    const float* bias     = (const float*)d_in[10];
    float* out = (float*)d_out;

    short*    A    = (short*)d_ws;                     // 24576 B
    float*    beff = (float*)((char*)d_ws + 24576);    // 24 B
    unsigned* dwt2 = (unsigned*)((char*)d_ws + 24608); // 1792 B
    unsigned* pwt2 = (unsigned*)((char*)d_ws + 26400); // 768 B

    hipLaunchKernelGGL(prep_kernel, dim3(49), dim3(256), 0, stream,
                       weight, b_off_pw, w_off_pw, b_off_dw, b_msk_pw, w_msk_pw, b_msk_dw,
                       w_off_dw, w_msk_dw, A, beff, dwt2, pwt2);
    hipLaunchKernelGGL(deform_main, dim3(LX / LT, NB), dim3(256), 0, stream,
                       x, bias, A, beff, dwt2, pwt2, out);
}